// Round 6
// baseline (47.671 us; speedup 1.0000x reference)
//
#include <hip/hip_runtime.h>
#include <math.h>

#define NB   2
#define NSEQ 1024
#define DD   256
#define LUTN 2048   // intervals; LUTN+1 entries over corr in [-1,1]

#define BM 128
#define BN 64
#define BK 32
#define MAGIC 0x5CA1AB1Eu

typedef _Float16 f16;
typedef _Float16 f16x8 __attribute__((ext_vector_type(8)));
typedef float f32x4 __attribute__((ext_vector_type(4)));

__device__ __forceinline__ float wrsum(float v) {
#pragma unroll
  for (int off = 32; off > 0; off >>= 1) v += __shfl_xor(v, off, 64);
  return v;
}

// Single fused kernel. Grid = 256 blocks (all co-resident on 256 CUs).
// Per block: [LUT slice -> flag] || [raw-fp32 GEMM with in-register f16 hi/lo
// split; row/col stats accumulated during staging] -> spin on flags ->
// epilogue (rank-1 centering correction, norm, clip, LUT interp, store).
__global__ __launch_bounds__(256) void fused_kernel(
    const float* __restrict__ fg, const float* __restrict__ sg,
    const float* __restrict__ w1, const float* __restrict__ b1,
    const float* __restrict__ w2, const float* __restrict__ b2,
    float* __restrict__ lut, unsigned* __restrict__ flags,
    float* __restrict__ out) {
  __shared__ __align__(16) f16 As[2][BM * 64];  // row*64: [hi slots 0-3 | lo 4-7], slot ^= row&7
  __shared__ __align__(16) f16 Bs[2][BN * 64];
  __shared__ float lut_s[LUTN + 1];
  __shared__ float mA[BM], rA[BM], mB[BN], rB[BN];

  const int t = threadIdx.x;
  const int lane = t & 63;
  const int w = t >> 6;
  const int wr = w >> 1, wc = w & 1;       // wave tile 64x32 at (wr*64, wc*32)

  const int bid = blockIdx.x;
  const int x = bid & 7, k = bid >> 3;     // XCD decode: 32 blocks per XCD
  const int panel = x + 8 * (k >> 4);      // 0..15
  const int bz  = panel >> 3;
  const int bm0 = (panel & 7) * BM;
  const int bn0 = (k & 15) * BN;

  const float* fb = fg + ((size_t)bz * NSEQ + bm0) * DD;
  const float* sb = sg + ((size_t)bz * NSEQ + bn0) * DD;

  float4 ra[2][2], rb[2];                  // raw staging regs
  float sA0 = 0.f, qA0 = 0.f, sA1 = 0.f, qA1 = 0.f, sB = 0.f, qB = 0.f;

  auto stage_load = [&](int st) {
#pragma unroll
    for (int j = 0; j < 2; ++j) {
      const int oi = t + 256 * j;          // row=oi>>2 (j=0: 0-63, j=1: 64-127), oct=oi&3
      const float* p = &fb[(size_t)(oi >> 2) * DD + st * BK + (oi & 3) * 8];
      ra[j][0] = *reinterpret_cast<const float4*>(p);
      ra[j][1] = *reinterpret_cast<const float4*>(p + 4);
    }
    {
      const float* p = &sb[(size_t)(t >> 2) * DD + st * BK + (t & 3) * 8];
      rb[0] = *reinterpret_cast<const float4*>(p);
      rb[1] = *reinterpret_cast<const float4*>(p + 4);
    }
  };

  auto split8 = [](const float4& u0, const float4& u1, f16x8& hv, f16x8& lv,
                   float& sm, float& sq) {
    const float vals[8] = {u0.x, u0.y, u0.z, u0.w, u1.x, u1.y, u1.z, u1.w};
#pragma unroll
    for (int e = 0; e < 8; ++e) {
      sm += vals[e];
      sq = fmaf(vals[e], vals[e], sq);
      const f16 h = (f16)vals[e];
      hv[e] = h;
      lv[e] = (f16)(vals[e] - (float)h);
    }
  };

  auto cvt_write = [&](int pbuf) {
    {
      const int r = t >> 2, o = t & 3;
      f16x8 hv, lv;
      split8(ra[0][0], ra[0][1], hv, lv, sA0, qA0);
      *reinterpret_cast<f16x8*>(&As[pbuf][r * 64 + ((o ^ (r & 7)) << 3)]) = hv;
      *reinterpret_cast<f16x8*>(&As[pbuf][r * 64 + (((4 + o) ^ (r & 7)) << 3)]) = lv;
    }
    {
      const int r = (t >> 2) + 64, o = t & 3;
      f16x8 hv, lv;
      split8(ra[1][0], ra[1][1], hv, lv, sA1, qA1);
      *reinterpret_cast<f16x8*>(&As[pbuf][r * 64 + ((o ^ (r & 7)) << 3)]) = hv;
      *reinterpret_cast<f16x8*>(&As[pbuf][r * 64 + (((4 + o) ^ (r & 7)) << 3)]) = lv;
    }
    {
      const int r = t >> 2, o = t & 3;
      f16x8 hv, lv;
      split8(rb[0], rb[1], hv, lv, sB, qB);
      *reinterpret_cast<f16x8*>(&Bs[pbuf][r * 64 + ((o ^ (r & 7)) << 3)]) = hv;
      *reinterpret_cast<f16x8*>(&Bs[pbuf][r * 64 + (((4 + o) ^ (r & 7)) << 3)]) = lv;
    }
  };

  stage_load(0);                           // issue first: hide HBM latency under LUT VALU

  // ---- LUT slice: 8 entries per block (+1 for block 0), then flag. ----
  {
    const float w1a = w1[lane], b1a = b1[lane], w2a = w2[lane];
    const float w1b = w1[lane + 64], b1b = b1[lane + 64], w2b = w2[lane + 64];
    const float b2v = b2[0];
#pragma unroll
    for (int jj = 0; jj < 3; ++jj) {
      int e;
      if (jj < 2) e = bid * 8 + w + jj * 4;
      else if (bid == 0 && w == 0) e = LUTN;
      else break;
      const float corr = -1.0f + (float)e * (2.0f / LUTN);
      const float a = expf(corr);
      const float x0 = fmaf(a, w1a, b1a);
      const float x1 = fmaf(a, w1b, b1b);
      const float g0 = 0.5f * x0 * (1.0f + erff(x0 * 0.70710678118654752f));
      const float g1 = 0.5f * x1 * (1.0f + erff(x1 * 0.70710678118654752f));
      float acc2 = fmaf(g1, w2b, g0 * w2a);
      acc2 = wrsum(acc2);
      if (lane == 0) lut[e] = acc2 + b2v;
    }
    __threadfence();
    __syncthreads();
    if (t == 0) atomicExch(&flags[bid], MAGIC);
  }

  f32x4 acc[4][2] = {};
  const int kslot = lane >> 4;

  cvt_write(0);
  __syncthreads();

  for (int st = 0; st < DD / BK; ++st) {
    const int p = st & 1;
    if (st < DD / BK - 1) stage_load(st + 1);
    f16x8 ah[4], al[4], bh[2], bl[2];
#pragma unroll
    for (int i = 0; i < 4; ++i) {
      const int r = wr * 64 + 16 * i + (lane & 15);
      ah[i] = *reinterpret_cast<const f16x8*>(&As[p][r * 64 + ((kslot ^ (r & 7)) << 3)]);
      al[i] = *reinterpret_cast<const f16x8*>(&As[p][r * 64 + (((4 + kslot) ^ (r & 7)) << 3)]);
    }
#pragma unroll
    for (int j = 0; j < 2; ++j) {
      const int r = wc * 32 + 16 * j + (lane & 15);
      bh[j] = *reinterpret_cast<const f16x8*>(&Bs[p][r * 64 + ((kslot ^ (r & 7)) << 3)]);
      bl[j] = *reinterpret_cast<const f16x8*>(&Bs[p][r * 64 + (((4 + kslot) ^ (r & 7)) << 3)]);
    }
#pragma unroll
    for (int i = 0; i < 4; ++i)
#pragma unroll
      for (int j = 0; j < 2; ++j) {
        acc[i][j] = __builtin_amdgcn_mfma_f32_16x16x32_f16(ah[i], bh[j], acc[i][j], 0, 0, 0);
        acc[i][j] = __builtin_amdgcn_mfma_f32_16x16x32_f16(ah[i], bl[j], acc[i][j], 0, 0, 0);
        acc[i][j] = __builtin_amdgcn_mfma_f32_16x16x32_f16(al[i], bh[j], acc[i][j], 0, 0, 0);
      }
    if (st < DD / BK - 1) cvt_write(p ^ 1);
    __syncthreads();
  }

  // ---- Fold per-thread stats (4 threads per row) and publish to LDS. ----
  auto red4 = [](float v) {
    v += __shfl_xor(v, 1, 64);
    v += __shfl_xor(v, 2, 64);
    return v;
  };
  sA0 = red4(sA0); qA0 = red4(qA0);
  sA1 = red4(sA1); qA1 = red4(qA1);
  sB  = red4(sB);  qB  = red4(qB);
  if ((t & 3) == 0) {
    const int r = t >> 2;  // 0..63
    const float m0 = sA0 * (1.0f / DD);
    mA[r] = m0;
    rA[r] = 1.0f / fmaxf(sqrtf(fmaxf(qA0 - (float)DD * m0 * m0, 0.0f)), 1e-6f);
    const float m1 = sA1 * (1.0f / DD);
    mA[r + 64] = m1;
    rA[r + 64] = 1.0f / fmaxf(sqrtf(fmaxf(qA1 - (float)DD * m1 * m1, 0.0f)), 1e-6f);
    const float mb_ = sB * (1.0f / DD);
    mB[r] = mb_;
    rB[r] = 1.0f / fmaxf(sqrtf(fmaxf(qB - (float)DD * mb_ * mb_, 0.0f)), 1e-6f);
  }

  // ---- Wait for all LUT slices, then stage LUT into LDS. ----
  while (__hip_atomic_load(&flags[t], __ATOMIC_RELAXED, __HIP_MEMORY_SCOPE_AGENT) != MAGIC) {}
  __threadfence();
  __syncthreads();
  for (int i = t; i <= LUTN; i += 256) lut_s[i] = lut[i];
  __syncthreads();

  // ---- Epilogue: rank-1 centering correction -> corr -> LUT -> store. ----
  float msv[2], rsv[2];
#pragma unroll
  for (int j = 0; j < 2; ++j) {
    const int cl = wc * 32 + 16 * j + (lane & 15);
    msv[j] = mB[cl];
    rsv[j] = rB[cl];
  }
#pragma unroll
  for (int i = 0; i < 4; ++i) {
#pragma unroll
    for (int rg = 0; rg < 4; ++rg) {
      const int rowl = wr * 64 + 16 * i + 4 * (lane >> 4) + rg;
      const float mfv = mA[rowl];
      const float rfv = rA[rowl];
#pragma unroll
      for (int j = 0; j < 2; ++j) {
        // cov_centered/16 = rawdot/16 - 16*mf*ms   (256/16 = 16)
        const float cov = acc[i][j][rg] * (1.0f / 16.0f) - 16.0f * mfv * msv[j];
        float corr = fminf(fmaxf(cov * rfv * rsv[j], -1.0f), 1.0f);
        const float tf = (corr + 1.0f) * (float)(LUTN / 2);
        int idx = (int)tf;
        idx = idx > (LUTN - 1) ? (LUTN - 1) : idx;
        const float fr = tf - (float)idx;
        const float lo = lut_s[idx], hi = lut_s[idx + 1];
        out[((size_t)bz * NSEQ + bm0 + rowl) * NSEQ + bn0 + wc * 32 + 16 * j + (lane & 15)]
            = fmaf(fr, hi - lo, lo);
      }
    }
  }
}

extern "C" void kernel_launch(void* const* d_in, const int* in_sizes, int n_in,
                              void* d_out, int out_size, void* d_ws, size_t ws_size,
                              hipStream_t stream) {
  const float* f  = (const float*)d_in[0];
  const float* s  = (const float*)d_in[1];
  const float* w1 = (const float*)d_in[2];
  const float* b1 = (const float*)d_in[3];
  const float* w2 = (const float*)d_in[4];
  const float* b2 = (const float*)d_in[5];
  float* out = (float*)d_out;

  char* ws = (char*)d_ws;
  float* lut = (float*)(ws);                 // LUTN+1 floats
  unsigned* flags = (unsigned*)(ws + 16384); // 256 flags

  fused_kernel<<<256, 256, 0, stream>>>(f, s, w1, b1, w2, b2, lut, flags, out);
}

// Round 7
// 18.275 us; speedup vs baseline: 2.6085x; 2.6085x over previous
//
#include <hip/hip_runtime.h>
#include <math.h>

#define NB   2
#define NSEQ 1024
#define DD   256
#define LUTN 2048   // intervals; LUTN+1 entries over corr in [-1,1]

#define BM 128
#define BN 64
#define BK 32
#define MAGIC 0x5CA1AB1Eu

typedef _Float16 f16;
typedef _Float16 f16x8 __attribute__((ext_vector_type(8)));
typedef float f32x4 __attribute__((ext_vector_type(4)));

__device__ __forceinline__ float wrsum(float v) {
#pragma unroll
  for (int off = 32; off > 0; off >>= 1) v += __shfl_xor(v, off, 64);
  return v;
}

// Single fused kernel, fence-free cross-block LUT broadcast (relaxed
// agent-scope atomics only; no __threadfence -> no L2 writeback storms).
// 2-deep global->reg prefetch pipeline (two staging sets) to cover LLC
// latency with only 4 waves/CU.
__global__ __launch_bounds__(256) void fused_kernel(
    const float* __restrict__ fg, const float* __restrict__ sg,
    const float* __restrict__ w1, const float* __restrict__ b1,
    const float* __restrict__ w2, const float* __restrict__ b2,
    float* __restrict__ lut, unsigned* __restrict__ flags,
    float* __restrict__ out) {
  __shared__ __align__(16) f16 As[2][BM * 64];  // row*64: [hi slots 0-3 | lo 4-7], slot ^= row&7
  __shared__ __align__(16) f16 Bs[2][BN * 64];
  __shared__ float lut_s[LUTN + 1];
  __shared__ float mA[BM], rA[BM], mB[BN], rB[BN];

  const int t = threadIdx.x;
  const int lane = t & 63;
  const int w = t >> 6;
  const int wr = w >> 1, wc = w & 1;       // wave tile 64x32 at (wr*64, wc*32)

  const int bid = blockIdx.x;
  const int x = bid & 7, k = bid >> 3;     // XCD decode
  const int panel = x + 8 * (k >> 4);      // 0..15
  const int bz  = panel >> 3;
  const int bm0 = (panel & 7) * BM;
  const int bn0 = (k & 15) * BN;

  const float* fb = fg + ((size_t)bz * NSEQ + bm0) * DD;
  const float* sb = sg + ((size_t)bz * NSEQ + bn0) * DD;

  float4 ra0[2][2], rb0[2], ra1[2][2], rb1[2];   // two staging sets
  float sA0 = 0.f, qA0 = 0.f, sA1 = 0.f, qA1 = 0.f, sB = 0.f, qB = 0.f;

  auto stage_load = [&](float4 (&ra)[2][2], float4 (&rb)[2], int st) {
#pragma unroll
    for (int j = 0; j < 2; ++j) {
      const int oi = t + 256 * j;
      const float* p = &fb[(size_t)(oi >> 2) * DD + st * BK + (oi & 3) * 8];
      ra[j][0] = *reinterpret_cast<const float4*>(p);
      ra[j][1] = *reinterpret_cast<const float4*>(p + 4);
    }
    {
      const float* p = &sb[(size_t)(t >> 2) * DD + st * BK + (t & 3) * 8];
      rb[0] = *reinterpret_cast<const float4*>(p);
      rb[1] = *reinterpret_cast<const float4*>(p + 4);
    }
  };

  auto split8 = [](const float4& u0, const float4& u1, f16x8& hv, f16x8& lv,
                   float& sm, float& sq) {
    const float vals[8] = {u0.x, u0.y, u0.z, u0.w, u1.x, u1.y, u1.z, u1.w};
#pragma unroll
    for (int e = 0; e < 8; ++e) {
      sm += vals[e];
      sq = fmaf(vals[e], vals[e], sq);
      const f16 h = (f16)vals[e];
      hv[e] = h;
      lv[e] = (f16)(vals[e] - (float)h);
    }
  };

  auto cvt_write = [&](float4 (&ra)[2][2], float4 (&rb)[2], int pbuf) {
    {
      const int r = t >> 2, o = t & 3;
      f16x8 hv, lv;
      split8(ra[0][0], ra[0][1], hv, lv, sA0, qA0);
      *reinterpret_cast<f16x8*>(&As[pbuf][r * 64 + ((o ^ (r & 7)) << 3)]) = hv;
      *reinterpret_cast<f16x8*>(&As[pbuf][r * 64 + (((4 + o) ^ (r & 7)) << 3)]) = lv;
    }
    {
      const int r = (t >> 2) + 64, o = t & 3;
      f16x8 hv, lv;
      split8(ra[1][0], ra[1][1], hv, lv, sA1, qA1);
      *reinterpret_cast<f16x8*>(&As[pbuf][r * 64 + ((o ^ (r & 7)) << 3)]) = hv;
      *reinterpret_cast<f16x8*>(&As[pbuf][r * 64 + (((4 + o) ^ (r & 7)) << 3)]) = lv;
    }
    {
      const int r = t >> 2, o = t & 3;
      f16x8 hv, lv;
      split8(rb[0], rb[1], hv, lv, sB, qB);
      *reinterpret_cast<f16x8*>(&Bs[pbuf][r * 64 + ((o ^ (r & 7)) << 3)]) = hv;
      *reinterpret_cast<f16x8*>(&Bs[pbuf][r * 64 + (((4 + o) ^ (r & 7)) << 3)]) = lv;
    }
  };

  f32x4 acc[4][2] = {};
  const int kslot = lane >> 4;

  auto do_mfma = [&](int p) {
    f16x8 ah[4], al[4], bh[2], bl[2];
#pragma unroll
    for (int i = 0; i < 4; ++i) {
      const int r = wr * 64 + 16 * i + (lane & 15);
      ah[i] = *reinterpret_cast<const f16x8*>(&As[p][r * 64 + ((kslot ^ (r & 7)) << 3)]);
      al[i] = *reinterpret_cast<const f16x8*>(&As[p][r * 64 + (((4 + kslot) ^ (r & 7)) << 3)]);
    }
#pragma unroll
    for (int j = 0; j < 2; ++j) {
      const int r = wc * 32 + 16 * j + (lane & 15);
      bh[j] = *reinterpret_cast<const f16x8*>(&Bs[p][r * 64 + ((kslot ^ (r & 7)) << 3)]);
      bl[j] = *reinterpret_cast<const f16x8*>(&Bs[p][r * 64 + (((4 + kslot) ^ (r & 7)) << 3)]);
    }
#pragma unroll
    for (int i = 0; i < 4; ++i)
#pragma unroll
      for (int j = 0; j < 2; ++j) {
        acc[i][j] = __builtin_amdgcn_mfma_f32_16x16x32_f16(ah[i], bh[j], acc[i][j], 0, 0, 0);
        acc[i][j] = __builtin_amdgcn_mfma_f32_16x16x32_f16(ah[i], bl[j], acc[i][j], 0, 0, 0);
        acc[i][j] = __builtin_amdgcn_mfma_f32_16x16x32_f16(al[i], bh[j], acc[i][j], 0, 0, 0);
      }
  };

  stage_load(ra0, rb0, 0);                 // issue first: latency hides under LUT VALU

  // ---- LUT slice: stores via relaxed agent atomics (no fence needed). ----
  {
    const float w1a = w1[lane], b1a = b1[lane], w2a = w2[lane];
    const float w1b = w1[lane + 64], b1b = b1[lane + 64], w2b = w2[lane + 64];
    const float b2v = b2[0];
#pragma unroll
    for (int jj = 0; jj < 3; ++jj) {
      int e;
      if (jj < 2) e = bid * 8 + w + jj * 4;
      else if (bid == 0 && w == 0) e = LUTN;
      else break;
      const float corr = -1.0f + (float)e * (2.0f / LUTN);
      const float a = expf(corr);
      const float x0 = fmaf(a, w1a, b1a);
      const float x1 = fmaf(a, w1b, b1b);
      const float g0 = 0.5f * x0 * (1.0f + erff(x0 * 0.70710678118654752f));
      const float g1 = 0.5f * x1 * (1.0f + erff(x1 * 0.70710678118654752f));
      float acc2 = fmaf(g1, w2b, g0 * w2a);
      acc2 = wrsum(acc2);
      if (lane == 0)
        __hip_atomic_store(&lut[e], acc2 + b2v, __ATOMIC_RELAXED, __HIP_MEMORY_SCOPE_AGENT);
    }
  }

  cvt_write(ra0, rb0, 0);                  // consume set0 (tile 0)
  asm volatile("s_waitcnt vmcnt(0)" ::: "memory");  // drain lut atomic stores (cheap)
  __syncthreads();                         // buf0 ready + all waves drained
  if (t == 0)
    __hip_atomic_store(&flags[bid], MAGIC, __ATOMIC_RELAXED, __HIP_MEMORY_SCOPE_AGENT);

  stage_load(ra0, rb0, 1);                 // 2-deep pipeline: tiles 1 and 2 in flight
  stage_load(ra1, rb1, 2);

  // step s: MFMA tile s from buf[s&1]; write tile s+1 from set[s&1] into
  // buf[(s+1)&1]; reload set[s&1] <- tile s+3. Two steps per unrolled iter.
#pragma unroll
  for (int su = 0; su < 4; ++su) {
    {
      // step s = 2*su (even, p=0): uses set0 (tile 2su+1)
      do_mfma(0);
      cvt_write(ra0, rb0, 1);
      if (su < 3) stage_load(ra0, rb0, 2 * su + 3);
      __syncthreads();
    }
    {
      // step s = 2*su+1 (odd, p=1): uses set1 (tile 2su+2)
      do_mfma(1);
      if (su < 3) {
        cvt_write(ra1, rb1, 0);
        if (su < 2) stage_load(ra1, rb1, 2 * su + 4);
        __syncthreads();
      }
    }
  }

  // ---- Fold per-thread stats (4 threads per row) and publish to LDS. ----
  auto red4 = [](float v) {
    v += __shfl_xor(v, 1, 64);
    v += __shfl_xor(v, 2, 64);
    return v;
  };
  sA0 = red4(sA0); qA0 = red4(qA0);
  sA1 = red4(sA1); qA1 = red4(qA1);
  sB  = red4(sB);  qB  = red4(qB);
  if ((t & 3) == 0) {
    const int r = t >> 2;  // 0..63
    const float m0 = sA0 * (1.0f / DD);
    mA[r] = m0;
    rA[r] = 1.0f / fmaxf(sqrtf(fmaxf(qA0 - (float)DD * m0 * m0, 0.0f)), 1e-6f);
    const float m1 = sA1 * (1.0f / DD);
    mA[r + 64] = m1;
    rA[r + 64] = 1.0f / fmaxf(sqrtf(fmaxf(qA1 - (float)DD * m1 * m1, 0.0f)), 1e-6f);
    const float mb_ = sB * (1.0f / DD);
    mB[r] = mb_;
    rB[r] = 1.0f / fmaxf(sqrtf(fmaxf(qB - (float)DD * mb_ * mb_, 0.0f)), 1e-6f);
  }

  // ---- Wait for all LUT slices (relaxed agent atomics), stage LUT to LDS. ----
  while (__hip_atomic_load(&flags[t], __ATOMIC_RELAXED, __HIP_MEMORY_SCOPE_AGENT) != MAGIC) {}
  __syncthreads();
  for (int i = t; i <= LUTN; i += 256)
    lut_s[i] = __hip_atomic_load(&lut[i], __ATOMIC_RELAXED, __HIP_MEMORY_SCOPE_AGENT);
  __syncthreads();

  // ---- Epilogue: rank-1 centering correction -> corr -> LUT -> store. ----
  float msv[2], rsv[2];
#pragma unroll
  for (int j = 0; j < 2; ++j) {
    const int cl = wc * 32 + 16 * j + (lane & 15);
    msv[j] = mB[cl];
    rsv[j] = rB[cl];
  }
#pragma unroll
  for (int i = 0; i < 4; ++i) {
#pragma unroll
    for (int rg = 0; rg < 4; ++rg) {
      const int rowl = wr * 64 + 16 * i + 4 * (lane >> 4) + rg;
      const float mfv = mA[rowl];
      const float rfv = rA[rowl];
#pragma unroll
      for (int j = 0; j < 2; ++j) {
        // cov_centered/16 = rawdot/16 - 16*mf*ms   (256/16 = 16)
        const float cov = acc[i][j][rg] * (1.0f / 16.0f) - 16.0f * mfv * msv[j];
        float corr = fminf(fmaxf(cov * rfv * rsv[j], -1.0f), 1.0f);
        const float tf = (corr + 1.0f) * (float)(LUTN / 2);
        int idx = (int)tf;
        idx = idx > (LUTN - 1) ? (LUTN - 1) : idx;
        const float fr = tf - (float)idx;
        const float lo = lut_s[idx], hi = lut_s[idx + 1];
        out[((size_t)bz * NSEQ + bm0 + rowl) * NSEQ + bn0 + wc * 32 + 16 * j + (lane & 15)]
            = fmaf(fr, hi - lo, lo);
      }
    }
  }
}

extern "C" void kernel_launch(void* const* d_in, const int* in_sizes, int n_in,
                              void* d_out, int out_size, void* d_ws, size_t ws_size,
                              hipStream_t stream) {
  const float* f  = (const float*)d_in[0];
  const float* s  = (const float*)d_in[1];
  const float* w1 = (const float*)d_in[2];
  const float* b1 = (const float*)d_in[3];
  const float* w2 = (const float*)d_in[4];
  const float* b2 = (const float*)d_in[5];
  float* out = (float*)d_out;

  char* ws = (char*)d_ws;
  float* lut = (float*)(ws);                 // LUTN+1 floats
  unsigned* flags = (unsigned*)(ws + 16384); // 256 flags

  fused_kernel<<<256, 256, 0, stream>>>(f, s, w1, b1, w2, b2, lut, flags, out);
}